// Round 1
// baseline (170.441 us; speedup 1.0000x reference)
//
#include <hip/hip_runtime.h>
#include <math.h>

#define BLOCK 256
#define MAXG  64

// log(sigmoid(x)) = -softplus(-x), numerically stable
__device__ __forceinline__ float log_sig(float x) {
    return (x >= 0.0f) ? (-log1pf(expf(-x))) : (x - log1pf(expf(x)));
}

__global__ __launch_bounds__(BLOCK) void fcos_main(
    const float* __restrict__ loc,    // N x 3
    const float* __restrict__ clsp,   // B x N x C
    const float* __restrict__ boxp,   // B x N x 6
    const float* __restrict__ ctrp,   // B x N
    const float* __restrict__ bboxes, // B x G x 6
    const int*   __restrict__ glab,   // B x G
    const float* __restrict__ spt,    // N
    const float* __restrict__ soi,    // N x 2
    int N, int G, int C,
    double* __restrict__ sums,        // [cls, box_num, w_sum, ctr_sum]
    unsigned int* __restrict__ npos)
{
    __shared__ float sbb[MAXG * 6];
    __shared__ float sarea[MAXG];
    __shared__ int   slab[MAXG];

    const int b = blockIdx.y;
    const int i = blockIdx.x * BLOCK + threadIdx.x;

    for (int k = threadIdx.x; k < G * 6; k += BLOCK)
        sbb[k] = bboxes[(size_t)b * G * 6 + k];
    for (int k = threadIdx.x; k < G; k += BLOCK) {
        slab[k] = glab[b * G + k];
        const float* p = bboxes + ((size_t)b * G + k) * 6;
        // match jnp.prod order: ((d0*d1)*d2)
        sarea[k] = (p[3] - p[0]) * (p[4] - p[1]) * (p[5] - p[2]);
    }
    __syncthreads();

    double cls_acc = 0.0, box_acc = 0.0, w_acc = 0.0, ctr_acc = 0.0;
    unsigned int np_acc = 0;

    if (i < N) {
        const float x  = loc[(size_t)i * 3 + 0];
        const float y  = loc[(size_t)i * 3 + 1];
        const float z  = loc[(size_t)i * 3 + 2];
        const float s  = spt[i];
        const float lo = soi[(size_t)i * 2 + 0];
        const float hi = soi[(size_t)i * 2 + 1];

        float best = 1e9f;  // INF, exactly representable in fp32
        int   bid  = 0;
        for (int g = 0; g < G; ++g) {
            const float b0 = sbb[g*6+0], b1 = sbb[g*6+1], b2 = sbb[g*6+2];
            const float b3 = sbb[g*6+3], b4 = sbb[g*6+4], b5 = sbb[g*6+5];
            const float l  = x - b0, t  = y - b1, f  = z - b2;
            const float r  = b3 - x, bt = b4 - y, a  = b5 - z;
            const float mx = fmaxf(fmaxf(fmaxf(l, t), fmaxf(f, r)), fmaxf(bt, a));
            const bool cared = (mx >= lo) && (mx <= hi);
            const float cx = (b0 + b3) * 0.5f, cy = (b1 + b4) * 0.5f, cz = (b2 + b5) * 0.5f;
            const float cminx = fmaxf(cx - s, b0), cmaxx = fminf(cx + s, b3);
            const float cminy = fmaxf(cy - s, b1), cmaxy = fminf(cy + s, b4);
            const float cminz = fmaxf(cz - s, b2), cmaxz = fminf(cz + s, b5);
            const float dmin = fminf(fminf(fminf(x - cminx, cmaxx - x),
                                           fminf(y - cminy, cmaxy - y)),
                                     fminf(z - cminz, cmaxz - z));
            const bool is_in = dmin > 0.0f;
            const float l2a = (is_in && cared) ? sarea[g] : 1e9f;
            if (l2a < best) { best = l2a; bid = g; }  // strict <: first-min, matches argmin
        }
        const int label = (best == 1e9f) ? 0 : slab[bid];

        // focal loss over all C classes (every location contributes)
        const float* cp = clsp + ((size_t)b * N + i) * (size_t)C;
        for (int c = 0; c < C; ++c) {
            const float xv = cp[c];
            const float p  = 1.0f / (1.0f + expf(-xv));
            if (label == c + 1) {
                const float om = 1.0f - p;
                cls_acc += (double)(-0.25f * om * om * log_sig(xv));
            } else {
                cls_acc += (double)(-0.75f * p * p * log_sig(-xv));
            }
        }

        if (label > 0) {
            // recompute box_target for the assigned gt
            const float b0 = sbb[bid*6+0], b1 = sbb[bid*6+1], b2 = sbb[bid*6+2];
            const float b3 = sbb[bid*6+3], b4 = sbb[bid*6+4], b5 = sbb[bid*6+5];
            const float l  = x - b0, t  = y - b1, f  = z - b2;
            const float r  = b3 - x, bb = b4 - y, a  = b5 - z;

            // centerness: ((lr)*(tb))*(fb), clip [1e-8,1], sqrt
            const float rx = fminf(l, r)  / fmaxf(l, r);
            const float ry = fminf(t, bb) / fmaxf(t, bb);
            const float rz = fminf(f, a)  / fmaxf(f, a);
            float c2 = rx * ry * rz;
            c2 = fminf(fmaxf(c2, 1e-8f), 1.0f);
            const float ct = sqrtf(c2);

            // IoU loss
            const float* bp = boxp + ((size_t)b * N + i) * 6;
            const float p0 = bp[0], p1 = bp[1], p2 = bp[2];
            const float p3 = bp[3], p4 = bp[4], p5 = bp[5];
            const float pv = (p0 + p3) * (p1 + p4) * (p2 + p5);
            const float tv = (l + r) * (t + bb) * (f + a);
            const float m0 = fminf(p0, l), m1 = fminf(p1, t),  m2 = fminf(p2, f);
            const float m3 = fminf(p3, r), m4 = fminf(p4, bb), m5 = fminf(p5, a);
            const float inter = (m0 + m3) * (m1 + m4) * (m2 + m5);
            const float uni   = pv + tv - inter;
            const float iou   = (inter + 1.0f) / (uni + 1.0f);
            const float il    = -logf(fmaxf(iou, 1e-6f));
            box_acc = (double)(il * ct);
            w_acc   = (double)ct;

            // centerness BCE
            const float cv  = ctrp[(size_t)b * N + i];
            const float bce = fmaxf(cv, 0.0f) - cv * ct + log1pf(expf(-fabsf(cv)));
            ctr_acc = (double)bce;
            np_acc  = 1;
        }
    }

    // wave-64 butterfly reduce, then one atomic per wave
    for (int off = 32; off > 0; off >>= 1) {
        cls_acc += __shfl_down(cls_acc, off, 64);
        box_acc += __shfl_down(box_acc, off, 64);
        w_acc   += __shfl_down(w_acc,   off, 64);
        ctr_acc += __shfl_down(ctr_acc, off, 64);
        np_acc  += __shfl_down(np_acc,  off, 64);
    }
    if ((threadIdx.x & 63) == 0) {
        atomicAdd(&sums[0], cls_acc);
        atomicAdd(&sums[1], box_acc);
        atomicAdd(&sums[2], w_acc);
        atomicAdd(&sums[3], ctr_acc);
        atomicAdd(npos, np_acc);
    }
}

__global__ void fcos_final(const double* __restrict__ sums,
                           const unsigned int* __restrict__ npos,
                           float* __restrict__ out, int B)
{
    const unsigned int np = *npos;
    out[0] = (float)(sums[0] / (double)(np + (unsigned int)B));
    out[1] = (float)(sums[1] / fmax(sums[2], 1e-8));
    out[2] = (float)(sums[3] / (double)(np >= 1u ? np : 1u));
}

extern "C" void kernel_launch(void* const* d_in, const int* in_sizes, int n_in,
                              void* d_out, int out_size, void* d_ws, size_t ws_size,
                              hipStream_t stream) {
    const float* loc  = (const float*)d_in[0];
    const float* clsp = (const float*)d_in[1];
    const float* boxp = (const float*)d_in[2];
    const float* ctrp = (const float*)d_in[3];
    const float* bbox = (const float*)d_in[4];
    const int*   glab = (const int*)d_in[5];
    // d_in[6] = gt_centers (unused by the reference computation)
    const float* spt  = (const float*)d_in[7];
    const float* soi  = (const float*)d_in[8];

    const int N = in_sizes[7];                 // strides_pt: (N,)
    const int B = in_sizes[3] / N;             // center_pred: (B,N)
    const int G = in_sizes[5] / B;             // gt_labels: (B,G)
    const int C = in_sizes[1] / in_sizes[3];   // cls_pred: (B,N,C)

    double* sums = (double*)d_ws;
    unsigned int* npos = (unsigned int*)((char*)d_ws + 4 * sizeof(double));

    // zero accumulators every call (graph replays must be deterministic)
    hipMemsetAsync(d_ws, 0, 4 * sizeof(double) + sizeof(unsigned int), stream);

    dim3 grid((N + BLOCK - 1) / BLOCK, B);
    fcos_main<<<grid, BLOCK, 0, stream>>>(loc, clsp, boxp, ctrp, bbox, glab, spt, soi,
                                          N, G, C, sums, npos);
    fcos_final<<<1, 1, 0, stream>>>(sums, npos, (float*)d_out, B);
}

// Round 2
// 33.869 us; speedup vs baseline: 5.0324x; 5.0324x over previous
//
#include <hip/hip_runtime.h>
#include <math.h>

#define BLOCK 256
#define MAXG  64
#define NSUM  5   // [cls, box_num, w_sum, ctr_sum, npos]

// log(sigmoid(x)) = -softplus(-x), numerically stable
__device__ __forceinline__ float log_sig(float x) {
    return (x >= 0.0f) ? (-log1pf(expf(-x))) : (x - log1pf(expf(x)));
}

__global__ __launch_bounds__(BLOCK) void fcos_main(
    const float* __restrict__ loc,    // N x 3
    const float* __restrict__ clsp,   // B x N x C
    const float* __restrict__ boxp,   // B x N x 6
    const float* __restrict__ ctrp,   // B x N
    const float* __restrict__ bboxes, // B x G x 6
    const int*   __restrict__ glab,   // B x G
    const float* __restrict__ spt,    // N
    const float* __restrict__ soi,    // N x 2
    int N, int G, int C,
    double* __restrict__ part)        // nblk x NSUM partials
{
    __shared__ float sbb[MAXG * 6];
    __shared__ float sarea[MAXG];
    __shared__ int   slab[MAXG];
    __shared__ double sred[(BLOCK / 64) * NSUM];

    const int b = blockIdx.y;
    const int i = blockIdx.x * BLOCK + threadIdx.x;

    for (int k = threadIdx.x; k < G * 6; k += BLOCK)
        sbb[k] = bboxes[(size_t)b * G * 6 + k];
    for (int k = threadIdx.x; k < G; k += BLOCK) {
        slab[k] = glab[b * G + k];
        const float* p = bboxes + ((size_t)b * G + k) * 6;
        sarea[k] = (p[3] - p[0]) * (p[4] - p[1]) * (p[5] - p[2]);
    }
    __syncthreads();

    double cls_acc = 0.0, box_acc = 0.0, w_acc = 0.0, ctr_acc = 0.0, np_acc = 0.0;

    if (i < N) {
        const float x  = loc[(size_t)i * 3 + 0];
        const float y  = loc[(size_t)i * 3 + 1];
        const float z  = loc[(size_t)i * 3 + 2];
        const float s  = spt[i];
        const float lo = soi[(size_t)i * 2 + 0];
        const float hi = soi[(size_t)i * 2 + 1];

        float best = 1e9f;  // INF, exactly representable in fp32
        int   bid  = 0;
        for (int g = 0; g < G; ++g) {
            const float b0 = sbb[g*6+0], b1 = sbb[g*6+1], b2 = sbb[g*6+2];
            const float b3 = sbb[g*6+3], b4 = sbb[g*6+4], b5 = sbb[g*6+5];
            const float l  = x - b0, t  = y - b1, f  = z - b2;
            const float r  = b3 - x, bt = b4 - y, a  = b5 - z;
            const float mx = fmaxf(fmaxf(fmaxf(l, t), fmaxf(f, r)), fmaxf(bt, a));
            const bool cared = (mx >= lo) && (mx <= hi);
            const float cx = (b0 + b3) * 0.5f, cy = (b1 + b4) * 0.5f, cz = (b2 + b5) * 0.5f;
            const float cminx = fmaxf(cx - s, b0), cmaxx = fminf(cx + s, b3);
            const float cminy = fmaxf(cy - s, b1), cmaxy = fminf(cy + s, b4);
            const float cminz = fmaxf(cz - s, b2), cmaxz = fminf(cz + s, b5);
            const float dmin = fminf(fminf(fminf(x - cminx, cmaxx - x),
                                           fminf(y - cminy, cmaxy - y)),
                                     fminf(z - cminz, cmaxz - z));
            const bool is_in = dmin > 0.0f;
            const float l2a = (is_in && cared) ? sarea[g] : 1e9f;
            if (l2a < best) { best = l2a; bid = g; }  // strict <: first-min, matches argmin
        }
        const int label = (best == 1e9f) ? 0 : slab[bid];

        // focal loss over all C classes (every location contributes)
        const float* cp = clsp + ((size_t)b * N + i) * (size_t)C;
        for (int c = 0; c < C; ++c) {
            const float xv = cp[c];
            const float p  = 1.0f / (1.0f + expf(-xv));
            if (label == c + 1) {
                const float om = 1.0f - p;
                cls_acc += (double)(-0.25f * om * om * log_sig(xv));
            } else {
                cls_acc += (double)(-0.75f * p * p * log_sig(-xv));
            }
        }

        if (label > 0) {
            const float b0 = sbb[bid*6+0], b1 = sbb[bid*6+1], b2 = sbb[bid*6+2];
            const float b3 = sbb[bid*6+3], b4 = sbb[bid*6+4], b5 = sbb[bid*6+5];
            const float l  = x - b0, t  = y - b1, f  = z - b2;
            const float r  = b3 - x, bb = b4 - y, a  = b5 - z;

            const float rx = fminf(l, r)  / fmaxf(l, r);
            const float ry = fminf(t, bb) / fmaxf(t, bb);
            const float rz = fminf(f, a)  / fmaxf(f, a);
            float c2 = rx * ry * rz;
            c2 = fminf(fmaxf(c2, 1e-8f), 1.0f);
            const float ct = sqrtf(c2);

            const float* bp = boxp + ((size_t)b * N + i) * 6;
            const float p0 = bp[0], p1 = bp[1], p2 = bp[2];
            const float p3 = bp[3], p4 = bp[4], p5 = bp[5];
            const float pv = (p0 + p3) * (p1 + p4) * (p2 + p5);
            const float tv = (l + r) * (t + bb) * (f + a);
            const float m0 = fminf(p0, l), m1 = fminf(p1, t),  m2 = fminf(p2, f);
            const float m3 = fminf(p3, r), m4 = fminf(p4, bb), m5 = fminf(p5, a);
            const float inter = (m0 + m3) * (m1 + m4) * (m2 + m5);
            const float uni   = pv + tv - inter;
            const float iou   = (inter + 1.0f) / (uni + 1.0f);
            const float il    = -logf(fmaxf(iou, 1e-6f));
            box_acc = (double)(il * ct);
            w_acc   = (double)ct;

            const float cv  = ctrp[(size_t)b * N + i];
            const float bce = fmaxf(cv, 0.0f) - cv * ct + log1pf(expf(-fabsf(cv)));
            ctr_acc = (double)bce;
            np_acc  = 1.0;
        }
    }

    // wave-64 reduce
    for (int off = 32; off > 0; off >>= 1) {
        cls_acc += __shfl_down(cls_acc, off, 64);
        box_acc += __shfl_down(box_acc, off, 64);
        w_acc   += __shfl_down(w_acc,   off, 64);
        ctr_acc += __shfl_down(ctr_acc, off, 64);
        np_acc  += __shfl_down(np_acc,  off, 64);
    }
    const int wave = threadIdx.x >> 6;
    if ((threadIdx.x & 63) == 0) {
        sred[wave * NSUM + 0] = cls_acc;
        sred[wave * NSUM + 1] = box_acc;
        sred[wave * NSUM + 2] = w_acc;
        sred[wave * NSUM + 3] = ctr_acc;
        sred[wave * NSUM + 4] = np_acc;
    }
    __syncthreads();

    // cross-wave reduce + one uncontended store per block (no atomics)
    if (threadIdx.x < NSUM) {
        double v = 0.0;
        for (int w = 0; w < BLOCK / 64; ++w) v += sred[w * NSUM + threadIdx.x];
        const size_t blk = (size_t)blockIdx.y * gridDim.x + blockIdx.x;
        part[blk * NSUM + threadIdx.x] = v;
    }
}

__global__ __launch_bounds__(BLOCK) void fcos_final(
    const double* __restrict__ part, int nblk,
    float* __restrict__ out, int B)
{
    __shared__ double sh[NSUM][BLOCK];
    double a[NSUM] = {0.0, 0.0, 0.0, 0.0, 0.0};
    for (int k = threadIdx.x; k < nblk; k += BLOCK) {
        const double* p = part + (size_t)k * NSUM;
        for (int j = 0; j < NSUM; ++j) a[j] += p[j];
    }
    for (int j = 0; j < NSUM; ++j) sh[j][threadIdx.x] = a[j];
    __syncthreads();
    for (int sft = BLOCK / 2; sft > 0; sft >>= 1) {
        if (threadIdx.x < sft)
            for (int j = 0; j < NSUM; ++j) sh[j][threadIdx.x] += sh[j][threadIdx.x + sft];
        __syncthreads();
    }
    if (threadIdx.x == 0) {
        const double np = sh[4][0];
        out[0] = (float)(sh[0][0] / (np + (double)B));
        out[1] = (float)(sh[1][0] / fmax(sh[2][0], 1e-8));
        out[2] = (float)(sh[3][0] / fmax(np, 1.0));
    }
}

extern "C" void kernel_launch(void* const* d_in, const int* in_sizes, int n_in,
                              void* d_out, int out_size, void* d_ws, size_t ws_size,
                              hipStream_t stream) {
    const float* loc  = (const float*)d_in[0];
    const float* clsp = (const float*)d_in[1];
    const float* boxp = (const float*)d_in[2];
    const float* ctrp = (const float*)d_in[3];
    const float* bbox = (const float*)d_in[4];
    const int*   glab = (const int*)d_in[5];
    // d_in[6] = gt_centers (unused by the reference computation)
    const float* spt  = (const float*)d_in[7];
    const float* soi  = (const float*)d_in[8];

    const int N = in_sizes[7];                 // strides_pt: (N,)
    const int B = in_sizes[3] / N;             // center_pred: (B,N)
    const int G = in_sizes[5] / B;             // gt_labels: (B,G)
    const int C = in_sizes[1] / in_sizes[3];   // cls_pred: (B,N,C)

    const int gx = (N + BLOCK - 1) / BLOCK;
    const int nblk = gx * B;
    double* part = (double*)d_ws;              // nblk * NSUM doubles

    dim3 grid(gx, B);
    fcos_main<<<grid, BLOCK, 0, stream>>>(loc, clsp, boxp, ctrp, bbox, glab, spt, soi,
                                          N, G, C, part);
    fcos_final<<<1, BLOCK, 0, stream>>>(part, nblk, (float*)d_out, B);
}

// Round 3
// 28.107 us; speedup vs baseline: 6.0641x; 1.2050x over previous
//
#include <hip/hip_runtime.h>
#include <math.h>

#define BLOCK 256
#define LOCS  64          // locations per block; 4 lanes cooperate per location
#define MAXG  64
#define NSUM  5           // [cls, box_num, w_sum, ctr_sum, npos]

__global__ __launch_bounds__(BLOCK) void fcos_main(
    const float* __restrict__ loc,    // N x 3
    const float* __restrict__ clsp,   // B x N x C
    const float* __restrict__ boxp,   // B x N x 6
    const float* __restrict__ ctrp,   // B x N
    const float* __restrict__ bboxes, // B x G x 6
    const int*   __restrict__ glab,   // B x G
    const float* __restrict__ spt,    // N
    const float* __restrict__ soi,    // N x 2
    int N, int G, int C,
    double* __restrict__ part)        // nblk x NSUM partials
{
    // per-g struct: [0]=b0,b1,b2,b3  [1]=b4,b5,area,label_bits
    //               [2]=cminx,cminy,cminz,-  [3]=cmaxx,cmaxy,cmaxz,-
    __shared__ float4 sg[MAXG][4];
    __shared__ double sred[(BLOCK / 64) * NSUM];
    __shared__ int sUni;

    const int b    = blockIdx.y;
    const int blk0 = blockIdx.x * LOCS;

    if (threadIdx.x == 0) {
        const int last = min(blk0 + LOCS - 1, N - 1);
        sUni = (spt[blk0] == spt[last]) ? 1 : 0;   // stride uniform over block?
    }
    if (threadIdx.x < G) {
        const int g = threadIdx.x;
        const float* p = bboxes + ((size_t)b * G + g) * 6;
        const float b0 = p[0], b1 = p[1], b2 = p[2];
        const float b3 = p[3], b4 = p[4], b5 = p[5];
        const float s  = spt[blk0];                // block's stride (valid if sUni)
        const float cx = (b0 + b3) * 0.5f, cy = (b1 + b4) * 0.5f, cz = (b2 + b5) * 0.5f;
        const float area = (b3 - b0) * (b4 - b1) * (b5 - b2);  // jnp.prod order
        const int   lab  = glab[b * G + g];
        sg[g][0] = make_float4(b0, b1, b2, b3);
        sg[g][1] = make_float4(b4, b5, area, __int_as_float(lab));
        sg[g][2] = make_float4(fmaxf(cx - s, b0), fmaxf(cy - s, b1), fmaxf(cz - s, b2), 0.f);
        sg[g][3] = make_float4(fminf(cx + s, b3), fminf(cy + s, b4), fminf(cz + s, b5), 0.f);
    }
    __syncthreads();

    const int sub = threadIdx.x & 3;          // lane within 4-lane group
    const int i   = blk0 + (threadIdx.x >> 2);

    float cls = 0.f, box = 0.f, w = 0.f, ctr = 0.f, npv = 0.f;

    if (i < N) {
        const float x = loc[(size_t)i * 3 + 0];
        const float y = loc[(size_t)i * 3 + 1];
        const float z = loc[(size_t)i * 3 + 2];
        const float2 sh = *(const float2*)(soi + (size_t)i * 2);
        const float lo = sh.x, hi = sh.y;
        const bool uni = (sUni != 0);
        const float s = uni ? 0.f : spt[i];   // only needed on fallback path

        float best = 1e9f;   // INF, exactly representable in fp32
        int   bid  = 0;
        #pragma unroll 4
        for (int g = sub; g < G; g += 4) {
            const float4 q0 = sg[g][0];
            const float4 q1 = sg[g][1];
            const float l = x - q0.x, t  = y - q0.y, f = z - q0.z;
            const float r = q0.w - x, bb = q1.x - y, a = q1.y - z;
            const float mx = fmaxf(fmaxf(fmaxf(l, t), fmaxf(f, r)), fmaxf(bb, a));
            bool ok = (mx >= lo) & (mx <= hi);
            if (uni) {
                const float4 q2 = sg[g][2];
                const float4 q3 = sg[g][3];
                ok = ok & (x > q2.x) & (y > q2.y) & (z > q2.z)
                        & (x < q3.x) & (y < q3.y) & (z < q3.z);
            } else {
                const float cx = (q0.x + q0.w) * 0.5f;
                const float cy = (q0.y + q1.x) * 0.5f;
                const float cz = (q0.z + q1.y) * 0.5f;
                ok = ok & (x > fmaxf(cx - s, q0.x)) & (y > fmaxf(cy - s, q0.y))
                        & (z > fmaxf(cz - s, q0.z)) & (x < fminf(cx + s, q0.w))
                        & (y < fminf(cy + s, q1.x)) & (z < fminf(cz + s, q1.y));
            }
            const float l2a = ok ? q1.z : 1e9f;
            if (l2a < best) { best = l2a; bid = g; }  // strict <: first-min in own subset
        }
        // 4-lane argmin reduce, ties -> smallest g (matches jnp.argmin)
        #pragma unroll
        for (int off = 1; off < 4; off <<= 1) {
            const float ob   = __shfl_xor(best, off, 4);
            const int   obid = __shfl_xor(bid,  off, 4);
            if (ob < best || (ob == best && obid < bid)) { best = ob; bid = obid; }
        }
        const float* sgf = (const float*)&sg[0][0];
        const int label = (best < 1e9f) ? __float_as_int(sgf[bid * 16 + 7]) : 0;

        // focal loss: group covers all C classes; fast path C==8 (2/lane, float2)
        if (C == 8) {
            const float2 v2 = *(const float2*)(clsp + ((size_t)b * N + i) * 8 + sub * 2);
            const float vv[2] = {v2.x, v2.y};
            #pragma unroll
            for (int k = 0; k < 2; ++k) {
                const int   c = sub * 2 + k;
                const float v = vv[k];
                const float e  = __expf(-fabsf(v));
                const float sp = __logf(1.0f + e);          // softplus(-|v|)
                const float lsm = fminf(v, 0.f) - sp;       // log sigmoid(v)
                const float lsn = -fmaxf(v, 0.f) - sp;      // log sigmoid(-v)
                const float inv = 1.0f / (1.0f + e);
                const float p   = (v >= 0.f) ? inv : e * inv;
                cls += (label == c + 1) ? -0.25f * (1.f - p) * (1.f - p) * lsm
                                        : -0.75f * p * p * lsn;
            }
        } else {
            for (int c = sub; c < C; c += 4) {
                const float v = clsp[((size_t)b * N + i) * (size_t)C + c];
                const float e  = __expf(-fabsf(v));
                const float sp = __logf(1.0f + e);
                const float lsm = fminf(v, 0.f) - sp;
                const float lsn = -fmaxf(v, 0.f) - sp;
                const float inv = 1.0f / (1.0f + e);
                const float p   = (v >= 0.f) ? inv : e * inv;
                cls += (label == c + 1) ? -0.25f * (1.f - p) * (1.f - p) * lsm
                                        : -0.75f * p * p * lsn;
            }
        }

        if (label > 0 && sub == 0) {
            const float4 q0 = sg[bid][0];
            const float4 q1 = sg[bid][1];
            const float l = x - q0.x, t  = y - q0.y, f = z - q0.z;
            const float r = q0.w - x, bb = q1.x - y, a = q1.y - z;

            const float rx = fminf(l, r)  / fmaxf(l, r);
            const float ry = fminf(t, bb) / fmaxf(t, bb);
            const float rz = fminf(f, a)  / fmaxf(f, a);
            float c2 = rx * ry * rz;
            c2 = fminf(fmaxf(c2, 1e-8f), 1.0f);
            const float ct = sqrtf(c2);

            const float* bp = boxp + ((size_t)b * N + i) * 6;
            const float2 ba = *(const float2*)(bp);
            const float2 bbv = *(const float2*)(bp + 2);
            const float2 bc = *(const float2*)(bp + 4);
            const float p0 = ba.x, p1 = ba.y, p2 = bbv.x;
            const float p3 = bbv.y, p4 = bc.x, p5 = bc.y;
            const float pv = (p0 + p3) * (p1 + p4) * (p2 + p5);
            const float tv = (l + r) * (t + bb) * (f + a);
            const float m0 = fminf(p0, l), m1 = fminf(p1, t),  m2 = fminf(p2, f);
            const float m3 = fminf(p3, r), m4 = fminf(p4, bb), m5 = fminf(p5, a);
            const float inter = (m0 + m3) * (m1 + m4) * (m2 + m5);
            const float uni2  = pv + tv - inter;
            const float iou   = (inter + 1.0f) / (uni2 + 1.0f);
            const float il    = -__logf(fmaxf(iou, 1e-6f));
            box = il * ct;
            w   = ct;
            const float cv = ctrp[(size_t)b * N + i];
            ctr = fmaxf(cv, 0.f) - cv * ct + __logf(1.f + __expf(-fabsf(cv)));
            npv = 1.f;
        }
    }

    // wave-64 reduce in fp32 (block partial ~O(100): fp32 error ~1e-5, threshold 1.5)
    #pragma unroll
    for (int off = 32; off > 0; off >>= 1) {
        cls += __shfl_down(cls, off, 64);
        box += __shfl_down(box, off, 64);
        w   += __shfl_down(w,   off, 64);
        ctr += __shfl_down(ctr, off, 64);
        npv += __shfl_down(npv, off, 64);
    }
    const int wv = threadIdx.x >> 6;
    if ((threadIdx.x & 63) == 0) {
        sred[wv * NSUM + 0] = (double)cls;
        sred[wv * NSUM + 1] = (double)box;
        sred[wv * NSUM + 2] = (double)w;
        sred[wv * NSUM + 3] = (double)ctr;
        sred[wv * NSUM + 4] = (double)npv;
    }
    __syncthreads();
    if (threadIdx.x < NSUM) {
        double v = 0.0;
        for (int k = 0; k < BLOCK / 64; ++k) v += sred[k * NSUM + threadIdx.x];
        part[((size_t)blockIdx.y * gridDim.x + blockIdx.x) * NSUM + threadIdx.x] = v;
    }
}

__global__ __launch_bounds__(BLOCK) void fcos_final(
    const double* __restrict__ part, int nblk,
    float* __restrict__ out, int B)
{
    __shared__ double shm[NSUM][BLOCK];
    double a[NSUM] = {0.0, 0.0, 0.0, 0.0, 0.0};
    for (int k = threadIdx.x; k < nblk; k += BLOCK) {
        const double* p = part + (size_t)k * NSUM;
        #pragma unroll
        for (int j = 0; j < NSUM; ++j) a[j] += p[j];
    }
    #pragma unroll
    for (int j = 0; j < NSUM; ++j) shm[j][threadIdx.x] = a[j];
    __syncthreads();
    for (int sft = BLOCK / 2; sft > 0; sft >>= 1) {
        if (threadIdx.x < sft) {
            #pragma unroll
            for (int j = 0; j < NSUM; ++j) shm[j][threadIdx.x] += shm[j][threadIdx.x + sft];
        }
        __syncthreads();
    }
    if (threadIdx.x == 0) {
        const double np = shm[4][0];
        out[0] = (float)(shm[0][0] / (np + (double)B));
        out[1] = (float)(shm[1][0] / fmax(shm[2][0], 1e-8));
        out[2] = (float)(shm[3][0] / fmax(np, 1.0));
    }
}

extern "C" void kernel_launch(void* const* d_in, const int* in_sizes, int n_in,
                              void* d_out, int out_size, void* d_ws, size_t ws_size,
                              hipStream_t stream) {
    const float* loc  = (const float*)d_in[0];
    const float* clsp = (const float*)d_in[1];
    const float* boxp = (const float*)d_in[2];
    const float* ctrp = (const float*)d_in[3];
    const float* bbox = (const float*)d_in[4];
    const int*   glab = (const int*)d_in[5];
    // d_in[6] = gt_centers (unused by the reference computation)
    const float* spt  = (const float*)d_in[7];
    const float* soi  = (const float*)d_in[8];

    const int N = in_sizes[7];                 // strides_pt: (N,)
    const int B = in_sizes[3] / N;             // center_pred: (B,N)
    const int G = in_sizes[5] / B;             // gt_labels: (B,G)
    const int C = in_sizes[1] / in_sizes[3];   // cls_pred: (B,N,C)

    const int gx   = (N + LOCS - 1) / LOCS;
    const int nblk = gx * B;
    double* part = (double*)d_ws;              // nblk * NSUM doubles

    dim3 grid(gx, B);
    fcos_main<<<grid, BLOCK, 0, stream>>>(loc, clsp, boxp, ctrp, bbox, glab, spt, soi,
                                          N, G, C, part);
    fcos_final<<<1, BLOCK, 0, stream>>>(part, nblk, (float*)d_out, B);
}